// Round 15
// baseline (165.633 us; speedup 1.0000x reference)
//
#include <hip/hip_runtime.h>
#include <hip/hip_bf16.h>

#define N_NODES 50000
#define N_EDGES 800000
#define IN_DIM  128
#define OUT_DIM 256
#define NBUCK   196        // ceil(50000/256) coarse buckets (256 nodes each)
#define BCAP    4608       // per-bucket edge capacity: mean 4096 + 8 sigma

typedef short frag8 __attribute__((ext_vector_type(8)));   // 8 bf16 (4 VGPRs)
typedef float f32x4 __attribute__((ext_vector_type(4)));

__device__ __forceinline__ void split2(float x, ushort& hi, ushort& lo) {
    unsigned u = __float_as_uint(x);
    hi = (ushort)(u >> 16);
    float fhi = __uint_as_float(u & 0xFFFF0000u);
    float r = x - fhi;
    lo = (ushort)(__float_as_uint(r) >> 16);
}

__device__ __forceinline__ float silu_fast(float x) {
    return x * __builtin_amdgcn_rcpf(1.0f + __expf(-x));
}

// ======== frag-major layout ========
// Operand X (row-major logical [R][K]) stored as 1KB chunks:
//   chunk(tile, kt, plane p, lane l) = bf16[8] of X[tile*16 + (l&15)][kt*32 + (l>>4)*8 + j]
//   ushort offset = ((tile*(K/32) + kt)*2 + p)*512 + l*8

// ---------------- bucketA: coarse bin by dst>>8 (and src>>8), LDS hist ----------
__global__ __launch_bounds__(256) void bucketA_kernel(
    const int* __restrict__ src, const int* __restrict__ dst,
    int* __restrict__ gCursD, int* __restrict__ gCursS,
    uint* __restrict__ pairsD, ushort* __restrict__ srcB, int E)
{
    __shared__ ushort sE[2048], dE[2048];
    __shared__ int cntD[NBUCK], cntS[NBUCK], curD[NBUCK], curS[NBUCK];
    const int tid = threadIdx.x;
    const int e0 = blockIdx.x * 2048;
    for (int i = tid; i < NBUCK; i += 256) { cntD[i] = 0; cntS[i] = 0; }
    __syncthreads();
    #pragma unroll
    for (int q = 0; q < 8; ++q) {
        int e = e0 + q * 256 + tid;
        if (e < E) {
            int s = src[e], d = dst[e];          // both < 65536: fit ushort
            sE[q * 256 + tid] = (ushort)s;
            dE[q * 256 + tid] = (ushort)d;
            atomicAdd(&cntD[d >> 8], 1);
            atomicAdd(&cntS[s >> 8], 1);
        }
    }
    __syncthreads();
    if (tid < NBUCK) {
        curD[tid] = tid * BCAP + atomicAdd(&gCursD[tid], cntD[tid]);
        curS[tid] = tid * BCAP + atomicAdd(&gCursS[tid], cntS[tid]);
    }
    __syncthreads();
    #pragma unroll
    for (int q = 0; q < 8; ++q) {
        int e = e0 + q * 256 + tid;
        if (e < E) {
            int s = sE[q * 256 + tid];
            int d = dE[q * 256 + tid];
            int bd = d >> 8, bs = s >> 8;
            int p = atomicAdd(&curD[bd], 1);
            if (p < (bd + 1) * BCAP) pairsD[p] = ((uint)s << 8) | (uint)(d & 255);
            int p2 = atomicAdd(&curS[bs], 1);
            if (p2 < (bs + 1) * BCAP) srcB[p2] = (ushort)(s & 255);
        }
    }
}

// ---------------- bucketB: per-bucket fine CSR via LDS (no global atomics) ------
__global__ __launch_bounds__(256) void bucketB_kernel(
    const uint* __restrict__ pairsD, const ushort* __restrict__ srcB,
    const int* __restrict__ gCursD, const int* __restrict__ gCursS,
    ushort* __restrict__ edge_srcF, int2* __restrict__ begcnt,
    float* __restrict__ scale_src)
{
    __shared__ uint pE[BCAP];                     // 18.4 KB
    __shared__ int h[256], hS[256], sd[256], curs[256];
    const int b = blockIdx.x, tid = threadIdx.x;
    const int base = b * BCAP;
    const int cnt  = min(gCursD[b], BCAP);
    const int cntS = min(gCursS[b], BCAP);
    h[tid] = 0; hS[tid] = 0;
    __syncthreads();
    for (int i = tid; i < cnt; i += 256) {
        uint p = pairsD[base + i];
        pE[i] = p;
        atomicAdd(&h[p & 255], 1);
    }
    for (int i = tid; i < cntS; i += 256)
        atomicAdd(&hS[srcB[base + i]], 1);
    __syncthreads();
    int myc = h[tid];
    sd[tid] = myc;
    __syncthreads();
    #pragma unroll
    for (int off = 1; off < 256; off <<= 1) {
        int t = (tid >= off) ? sd[tid - off] : 0;
        __syncthreads();
        sd[tid] += t;
        __syncthreads();
    }
    int excl = sd[tid] - myc;
    int n = b * 256 + tid;
    if (n < N_NODES) {
        begcnt[n] = make_int2(base + excl, myc);
        scale_src[n] = rsqrtf(fmaxf((float)hS[tid], 1.0f));
    }
    curs[tid] = excl;
    __syncthreads();
    for (int i = tid; i < cnt; i += 256) {
        uint p = pE[i];
        int slot = atomicAdd(&curs[p & 255], 1);
        edge_srcF[base + slot] = (ushort)(p >> 8);
    }
}

// ---------------- W pre-split -> frag-major (all three weights) ----------------
__global__ __launch_bounds__(256) void wsplit_frag_kernel(
    const float* __restrict__ Wc, const float* __restrict__ W1,
    const float* __restrict__ W2, ushort* __restrict__ Wfc,
    ushort* __restrict__ Wf1, ushort* __restrict__ Wf2)
{
    int idx = blockIdx.x * 256 + threadIdx.x;
    const float* W; ushort* Wf; int K, off;
    if (idx < 4096)        { W = Wc; Wf = Wfc; K = 128; off = idx; }
    else if (idx < 12288)  { W = W1; Wf = Wf1; K = 256; off = idx - 4096; }
    else if (idx < 20480)  { W = W2; Wf = Wf2; K = 256; off = idx - 12288; }
    else return;
    int NK = K / 32;
    int l = off & 63;
    int kt = (K == 128) ? ((off >> 6) & 3) : ((off >> 6) & 7);
    int ct = (K == 128) ? (off >> 8) : (off >> 9);
    int col = ct * 16 + (l & 15);
    int kb  = kt * 32 + (l >> 4) * 8;
    frag8 vh, vl;
    #pragma unroll
    for (int q = 0; q < 8; ++q) {
        ushort hi, lo; split2(W[(size_t)(kb + q) * 256 + col], hi, lo);
        vh[q] = (short)hi; vl[q] = (short)lo;
    }
    ushort* dstp = Wf + ((size_t)(ct * NK + kt) * 2) * 512 + l * 8;
    *reinterpret_cast<frag8*>(dstp) = vh;
    *reinterpret_cast<frag8*>(dstp + 512) = vl;
}

// ---------------- transpose + pre-scale: feats -> featsT[8][N][16] ----------------
// featsT[s][n][0..15] = feats[n][s*16..] * rsqrt(deg_out[n]); each slice is a
// contiguous 3.2MB region (< 4MB per-XCD L2).
__global__ __launch_bounds__(256) void transpose_scale_kernel(
    const float* __restrict__ feats, const float* __restrict__ scale_src,
    float* __restrict__ featsT)
{
    __shared__ float t[64][132];   // 33.8 KB; 132 = 16B-aligned rows + bank rotate
    const int tid = threadIdx.x;
    const int node0 = blockIdx.x * 64;
    #pragma unroll
    for (int it = 0; it < 8; ++it) {
        int idx = it * 256 + tid;           // (nl<<5)|span
        int nl = idx >> 5, span = idx & 31;
        int n = node0 + nl;
        float4 v = make_float4(0, 0, 0, 0);
        if (n < N_NODES) {
            v = *reinterpret_cast<const float4*>(&feats[(size_t)n * IN_DIM + span * 4]);
            float sc = scale_src[n];
            v.x *= sc; v.y *= sc; v.z *= sc; v.w *= sc;
        }
        *reinterpret_cast<float4*>(&t[nl][span * 4]) = v;
    }
    __syncthreads();
    #pragma unroll
    for (int it = 0; it < 8; ++it) {
        int idx = it * 256 + tid;           // (s<<8)|(nl<<2)|sub
        int s = idx >> 8, nl = (idx >> 2) & 63, sub = idx & 3;
        int n = node0 + nl;
        if (n < N_NODES) {
            float4 v = *reinterpret_cast<const float4*>(&t[nl][s * 16 + sub * 4]);
            *reinterpret_cast<float4*>(&featsT[(size_t)s * N_NODES * 16 + (size_t)n * 16 + sub * 4]) = v;
        }
    }
}

// ---------------- gather8: L2-resident sliced gather -> frag-major aggF ---------
// Grid = 196 buckets x 8 slices; slice = blockIdx%8 tracks the XCD round-robin,
// so each XCD's blocks only touch one contiguous 3.2MB featsT slice (L2-hit
// gathers after first touch). featsT is pre-scaled: pure float4 sums.
__global__ __launch_bounds__(256) void gather8_kernel(
    const float* __restrict__ featsT, const ushort* __restrict__ edge_srcF,
    const int2* __restrict__ begcnt, ushort* __restrict__ aggF)
{
    __shared__ float ag[256][20];   // 20 KB -> 8 blocks/CU
    const int tid = threadIdx.x;
    const int slice  = blockIdx.x & 7;
    const int bucket = blockIdx.x >> 3;
    const float* fT = featsT + (size_t)slice * N_NODES * 16;

    #pragma unroll
    for (int p = 0; p < 4; ++p) {
        int nl  = p * 64 + (tid >> 2);
        int sub = tid & 3;
        int n   = bucket * 256 + nl;
        float4 a0 = make_float4(0, 0, 0, 0), a1 = make_float4(0, 0, 0, 0);
        float4 a2 = make_float4(0, 0, 0, 0), a3 = make_float4(0, 0, 0, 0);
        float dnm = 1.0f;
        if (n < N_NODES) {
            int2 bcn = begcnt[n];
            int j = bcn.x, jend = bcn.x + bcn.y;
            for (; j + 3 < jend; j += 4) {
                int s0 = edge_srcF[j],     s1 = edge_srcF[j + 1];
                int s2 = edge_srcF[j + 2], s3 = edge_srcF[j + 3];
                float4 v0 = *reinterpret_cast<const float4*>(&fT[(size_t)s0 * 16 + sub * 4]);
                float4 v1 = *reinterpret_cast<const float4*>(&fT[(size_t)s1 * 16 + sub * 4]);
                float4 v2 = *reinterpret_cast<const float4*>(&fT[(size_t)s2 * 16 + sub * 4]);
                float4 v3 = *reinterpret_cast<const float4*>(&fT[(size_t)s3 * 16 + sub * 4]);
                a0.x += v0.x; a0.y += v0.y; a0.z += v0.z; a0.w += v0.w;
                a1.x += v1.x; a1.y += v1.y; a1.z += v1.z; a1.w += v1.w;
                a2.x += v2.x; a2.y += v2.y; a2.z += v2.z; a2.w += v2.w;
                a3.x += v3.x; a3.y += v3.y; a3.z += v3.z; a3.w += v3.w;
            }
            for (; j < jend; ++j) {
                int s0 = edge_srcF[j];
                float4 v0 = *reinterpret_cast<const float4*>(&fT[(size_t)s0 * 16 + sub * 4]);
                a0.x += v0.x; a0.y += v0.y; a0.z += v0.z; a0.w += v0.w;
            }
            dnm = rsqrtf(fmaxf((float)bcn.y, 1.0f));
        }
        float4 o;
        o.x = (a0.x + a1.x + a2.x + a3.x) * dnm;
        o.y = (a0.y + a1.y + a2.y + a3.y) * dnm;
        o.z = (a0.z + a1.z + a2.z + a3.z) * dnm;
        o.w = (a0.w + a1.w + a2.w + a3.w) * dnm;
        *reinterpret_cast<float4*>(&ag[nl][sub * 4]) = o;
    }
    __syncthreads();

    // write-out: bf16 split -> frag-major aggF (256B coalesced runs)
    const int kt  = slice >> 1;
    #pragma unroll
    for (int it = 0; it < 8; ++it) {
        int idx   = it * 256 + tid;       // half(1) row(4) seg_i(1) plane(1) tile(4)
        int half  = idx & 1;
        int row   = (idx >> 1) & 15;
        int seg_i = (idx >> 5) & 1;
        int plane = (idx >> 6) & 1;
        int tile  = idx >> 7;             // 0..15
        int tile_g = bucket * 16 + tile;
        if (tile_g < N_NODES / 16) {
            int k_slice = seg_i * 8 + half * 4;
            float4 v = *reinterpret_cast<const float4*>(&ag[tile * 16 + row][k_slice]);
            ushort4 h4, l4;
            split2(v.x, h4.x, l4.x); split2(v.y, h4.y, l4.y);
            split2(v.z, h4.z, l4.z); split2(v.w, h4.w, l4.w);
            int seg = 2 * (slice & 1) + seg_i;
            int l = seg * 16 + row;
            size_t base = ((size_t)(tile_g * 4 + kt) * 2 + plane) * 512 + l * 8 + half * 4;
            *reinterpret_cast<ushort4*>(&aggF[base]) = plane ? l4 : h4;
        }
    }
}

// ---------------- fused 3-layer MLP (A from global aggF frag-major) -------------
template <int NK>
__device__ __forceinline__ void mfma_loop(
    const ushort* __restrict__ a0, const ushort* __restrict__ a1,
    const ushort* __restrict__ w0, const ushort* __restrict__ w1,
    const ushort* __restrict__ w2, const ushort* __restrict__ w3,
    f32x4 acc[2][4])
{
    #pragma unroll 2
    for (int kt = 0; kt < NK; ++kt) {
        const int o = kt * 1024;
        frag8 ah[2], al[2], bh[4], bl[4];
        ah[0] = *reinterpret_cast<const frag8*>(a0 + o);
        al[0] = *reinterpret_cast<const frag8*>(a0 + o + 512);
        ah[1] = *reinterpret_cast<const frag8*>(a1 + o);
        al[1] = *reinterpret_cast<const frag8*>(a1 + o + 512);
        bh[0] = *reinterpret_cast<const frag8*>(w0 + o);
        bl[0] = *reinterpret_cast<const frag8*>(w0 + o + 512);
        bh[1] = *reinterpret_cast<const frag8*>(w1 + o);
        bl[1] = *reinterpret_cast<const frag8*>(w1 + o + 512);
        bh[2] = *reinterpret_cast<const frag8*>(w2 + o);
        bl[2] = *reinterpret_cast<const frag8*>(w2 + o + 512);
        bh[3] = *reinterpret_cast<const frag8*>(w3 + o);
        bl[3] = *reinterpret_cast<const frag8*>(w3 + o + 512);
        #pragma unroll
        for (int m = 0; m < 2; ++m) {
            #pragma unroll
            for (int n = 0; n < 4; ++n) {
                acc[m][n] = __builtin_amdgcn_mfma_f32_16x16x32_bf16(ah[m], bh[n], acc[m][n], 0, 0, 0);
                acc[m][n] = __builtin_amdgcn_mfma_f32_16x16x32_bf16(ah[m], bl[n], acc[m][n], 0, 0, 0);
                acc[m][n] = __builtin_amdgcn_mfma_f32_16x16x32_bf16(al[m], bh[n], acc[m][n], 0, 0, 0);
            }
        }
    }
}

__global__ __launch_bounds__(256, 5) void fused_mlp_kernel(
    const ushort* __restrict__ aggF, const ushort* __restrict__ Wfc,
    const ushort* __restrict__ Wf1, const ushort* __restrict__ Wf2,
    const float* __restrict__ bc, const float* __restrict__ b1,
    const float* __restrict__ b2, float* __restrict__ out,
    int M, int maxTile)
{
    __shared__ ushort fb[16384];   // exactly 32 KB

    const int tid  = threadIdx.x;
    const int lane = tid & 63;
    const int wv   = tid >> 6;
    const int blk  = blockIdx.x;
    const int row0 = blk * 32;
    const int fr   = lane & 15;
    const int lg   = lane >> 4;
    const int fh   = fr >> 3;

    const int t0 = min(blk * 2,     maxTile);
    const int t1 = min(blk * 2 + 1, maxTile);

    ushort* fbase = fb + wv * 2048 + (lg << 5) + (fr & 7);
    const int lsw = (lane * 8) ^ ((lane >> 4) << 3);

    f32x4 acc[2][4];

    // ---- layer 1: K=128 (NK=4), A from global aggF ----
    {
        const ushort* a0 = aggF + ((size_t)t0 * 4 * 2) * 512 + lane * 8;
        const ushort* a1 = aggF + ((size_t)t1 * 4 * 2) * 512 + lane * 8;
        const ushort* w0 = Wfc + ((size_t)(wv * 4 + 0) * 4 * 2) * 512 + lane * 8;
        const ushort* w1 = Wfc + ((size_t)(wv * 4 + 1) * 4 * 2) * 512 + lane * 8;
        const ushort* w2 = Wfc + ((size_t)(wv * 4 + 2) * 4 * 2) * 512 + lane * 8;
        const ushort* w3 = Wfc + ((size_t)(wv * 4 + 3) * 4 * 2) * 512 + lane * 8;
        #pragma unroll
        for (int m = 0; m < 2; ++m)
            #pragma unroll
            for (int n = 0; n < 4; ++n) acc[m][n] = (f32x4)(0.f);
        mfma_loop<4>(a0, a1, w0, w1, w2, w3, acc);
    }

    // layer-1 epilogue: silu -> split -> fb (swizzled direct)
    #pragma unroll
    for (int n = 0; n < 4; ++n) {
        float b = bc[wv * 64 + n * 16 + fr];
        const int kseg = 2 * (n & 1) + fh;
        const int noff = (n >> 1) * 1024 + kseg * 128;
        #pragma unroll
        for (int m = 0; m < 2; ++m) {
            f32x4 v = acc[m][n];
            #pragma unroll
            for (int q = 0; q < 4; ++q) {
                float s = silu_fast(v[q] + b);
                ushort hi, lo; split2(s, hi, lo);
                const int o = m * 8192 + noff + (q ^ kseg) * 8;
                fbase[o]       = hi;
                fbase[o + 512] = lo;
            }
        }
    }
    __syncthreads();

    // ---- layer 2: K=256 (NK=8), A from fb (swizzled) ----
    {
        const ushort* a0 = fb + lsw;
        const ushort* a1 = fb + 8192 + lsw;
        const ushort* w0 = Wf1 + ((size_t)(wv * 4 + 0) * 8 * 2) * 512 + lane * 8;
        const ushort* w1 = Wf1 + ((size_t)(wv * 4 + 1) * 8 * 2) * 512 + lane * 8;
        const ushort* w2 = Wf1 + ((size_t)(wv * 4 + 2) * 8 * 2) * 512 + lane * 8;
        const ushort* w3 = Wf1 + ((size_t)(wv * 4 + 3) * 8 * 2) * 512 + lane * 8;
        #pragma unroll
        for (int m = 0; m < 2; ++m)
            #pragma unroll
            for (int n = 0; n < 4; ++n) acc[m][n] = (f32x4)(0.f);
        mfma_loop<8>(a0, a1, w0, w1, w2, w3, acc);
    }
    __syncthreads();   // all fb reads done before overwrite

    // layer-2 epilogue -> fb (swizzled direct)
    #pragma unroll
    for (int n = 0; n < 4; ++n) {
        float b = b1[wv * 64 + n * 16 + fr];
        const int kseg = 2 * (n & 1) + fh;
        const int noff = (n >> 1) * 1024 + kseg * 128;
        #pragma unroll
        for (int m = 0; m < 2; ++m) {
            f32x4 v = acc[m][n];
            #pragma unroll
            for (int q = 0; q < 4; ++q) {
                float s = silu_fast(v[q] + b);
                ushort hi, lo; split2(s, hi, lo);
                const int o = m * 8192 + noff + (q ^ kseg) * 8;
                fbase[o]       = hi;
                fbase[o + 512] = lo;
            }
        }
    }
    __syncthreads();

    // ---- layer 3: K=256 (NK=8), A from fb (swizzled) ----
    {
        const ushort* a0 = fb + lsw;
        const ushort* a1 = fb + 8192 + lsw;
        const ushort* w0 = Wf2 + ((size_t)(wv * 4 + 0) * 8 * 2) * 512 + lane * 8;
        const ushort* w1 = Wf2 + ((size_t)(wv * 4 + 1) * 8 * 2) * 512 + lane * 8;
        const ushort* w2 = Wf2 + ((size_t)(wv * 4 + 2) * 8 * 2) * 512 + lane * 8;
        const ushort* w3 = Wf2 + ((size_t)(wv * 4 + 3) * 8 * 2) * 512 + lane * 8;
        #pragma unroll
        for (int m = 0; m < 2; ++m)
            #pragma unroll
            for (int n = 0; n < 4; ++n) acc[m][n] = (f32x4)(0.f);
        mfma_loop<8>(a0, a1, w0, w1, w2, w3, acc);
    }

    // layer-3 epilogue: direct f32 global stores (64B-contiguous per 16 lanes)
    #pragma unroll
    for (int n = 0; n < 4; ++n) {
        int col = wv * 64 + n * 16 + fr;
        float b = b2[col];
        #pragma unroll
        for (int m = 0; m < 2; ++m) {
            int rowb = row0 + m * 16 + lg * 4;
            f32x4 v = acc[m][n];
            #pragma unroll
            for (int q = 0; q < 4; ++q) {
                int row = rowb + q;
                if (row < M)
                    out[(size_t)row * OUT_DIM + col] = silu_fast(v[q] + b);
            }
        }
    }
}

extern "C" void kernel_launch(void* const* d_in, const int* in_sizes, int n_in,
                              void* d_out, int out_size, void* d_ws, size_t ws_size,
                              hipStream_t stream)
{
    const float* feats  = (const float*)d_in[0];
    const float* W_conv = (const float*)d_in[1];
    const float* b_conv = (const float*)d_in[2];
    const float* W1     = (const float*)d_in[3];
    const float* b1     = (const float*)d_in[4];
    const float* W2     = (const float*)d_in[5];
    const float* b2     = (const float*)d_in[6];
    const int*   src    = (const int*)d_in[7];
    const int*   dst    = (const int*)d_in[8];

    // workspace layout (bytes):
    //   [0, 784)                 gCursD (196 ints)
    //   [1024, 1808)             gCursS
    //   [4096, 404,096)          begcnt (50000 int2)
    //   [404,096, 604,096)       scale_src (N f32)
    //   [1,000,000, 4,612,672)   pairsD  (196 x 4608 uint)
    //   [4,612,672, 6,419,008)   srcB    (196 x 4608 ushort)
    //   [6,420,480, 8,226,816)   edge_srcF (196 x 4608 ushort, padded CSR)
    //   [10,000,000, 35,600,000) featsT (8 x 50000 x 16 f32, pre-scaled slices)
    //   [55,000,064, 80,600,064) aggF frag tiles (3125 x 8KB)
    //   [80,600,064, 81,255,424) Wfc / Wf1 / Wf2 (frag-major bf16 planes)
    char* ws = (char*)d_ws;
    int*    gCursD    = (int*)(ws + 0);
    int*    gCursS    = (int*)(ws + 1024);
    int2*   begcnt    = (int2*)(ws + 4096);
    float*  scale_src = (float*)(ws + 404096);
    uint*   pairsD    = (uint*)(ws + 1000000);
    ushort* srcB      = (ushort*)(ws + 4612672);
    ushort* edge_srcF = (ushort*)(ws + 6420480);
    float*  featsT    = (float*)(ws + 10000000);
    ushort* aggF      = (ushort*)(ws + 55000064);
    ushort* Wfc       = (ushort*)(ws + 80600064);
    ushort* Wf1       = (ushort*)(ws + 80731136);
    ushort* Wf2       = (ushort*)(ws + 80993280);

    hipMemsetAsync(ws, 0, 2048, stream);   // zero gCursD + gCursS

    const int ablocks = (N_EDGES + 2047) / 2048;   // 391
    bucketA_kernel<<<ablocks, 256, 0, stream>>>(src, dst, gCursD, gCursS, pairsD, srcB, N_EDGES);
    bucketB_kernel<<<NBUCK, 256, 0, stream>>>(pairsD, srcB, gCursD, gCursS,
                                              edge_srcF, begcnt, scale_src);

    wsplit_frag_kernel<<<80, 256, 0, stream>>>(W_conv, W1, W2, Wfc, Wf1, Wf2);

    transpose_scale_kernel<<<(N_NODES + 63) / 64, 256, 0, stream>>>(feats, scale_src, featsT);

    gather8_kernel<<<NBUCK * 8, 256, 0, stream>>>(featsT, edge_srcF, begcnt, aggF);

    const int gblocks = (N_NODES + 31) / 32;   // 1563
    const int maxTile = N_NODES / 16 - 1;      // 3124
    fused_mlp_kernel<<<gblocks, 256, 0, stream>>>(aggF, Wfc, Wf1, Wf2,
                                                  b_conv, b1, b2,
                                                  (float*)d_out, N_NODES, maxTile);
}

// Round 16
// 150.383 us; speedup vs baseline: 1.1014x; 1.1014x over previous
//
#include <hip/hip_runtime.h>
#include <hip/hip_bf16.h>

#define N_NODES 50000
#define N_EDGES 800000
#define IN_DIM  128
#define OUT_DIM 256
#define NBUCK   196        // ceil(50000/256) coarse buckets (256 nodes each)
#define BCAP    4608       // per-bucket edge capacity: mean 4096 + 8 sigma

typedef short frag8 __attribute__((ext_vector_type(8)));   // 8 bf16 (4 VGPRs)
typedef float f32x4 __attribute__((ext_vector_type(4)));

__device__ __forceinline__ void split2(float x, ushort& hi, ushort& lo) {
    unsigned u = __float_as_uint(x);
    hi = (ushort)(u >> 16);
    float fhi = __uint_as_float(u & 0xFFFF0000u);
    float r = x - fhi;
    lo = (ushort)(__float_as_uint(r) >> 16);
}

__device__ __forceinline__ float silu_fast(float x) {
    return x * __builtin_amdgcn_rcpf(1.0f + __expf(-x));
}

// ======== frag-major layout ========
// Operand X (row-major logical [R][K]) stored as 1KB chunks:
//   chunk(tile, kt, plane p, lane l) = bf16[8] of X[tile*16 + (l&15)][kt*32 + (l>>4)*8 + j]
//   ushort offset = ((tile*(K/32) + kt)*2 + p)*512 + l*8

// ---------------- bucketA: LDS counting sort -> coalesced bucket writes ---------
// 391 blocks x 2048 edges. Per block: 196-bin histogram, LDS scan, LDS scatter
// into bucket-sorted order, then COALESCED global write-out (consecutive
// threads in a bucket hit consecutive addresses). 196 global atomics/block.
__global__ __launch_bounds__(256) void bucketA_kernel(
    const int* __restrict__ src, const int* __restrict__ dst,
    int* __restrict__ gCursD, int* __restrict__ gCursS,
    uint* __restrict__ pairsD, ushort* __restrict__ srcB, int E)
{
    __shared__ ushort sE[2048], dE[2048];      // 8 KB
    __shared__ uint   sortD[2048];             // 8 KB
    __shared__ ushort sortS[2048];             // 4 KB
    __shared__ int cntD[256], cntS[256];
    __shared__ int offD[256], offS[256];
    __shared__ int curD[256], curS[256];
    __shared__ int gBaseD[256], gBaseS[256];
    __shared__ int sd[256];

    const int tid = threadIdx.x;
    const int e0  = blockIdx.x * 2048;
    const int nE  = min(2048, E - e0);

    cntD[tid] = 0; cntS[tid] = 0;
    __syncthreads();
    #pragma unroll
    for (int q = 0; q < 8; ++q) {
        int i = q * 256 + tid;
        if (i < nE) {
            int s = src[e0 + i], d = dst[e0 + i];   // < 65536: fit ushort
            sE[i] = (ushort)s;
            dE[i] = (ushort)d;
            atomicAdd(&cntD[d >> 8], 1);
            atomicAdd(&cntS[s >> 8], 1);
        }
    }
    __syncthreads();

    // exclusive scan of cntD over 256 (bins 196..255 are zero)
    int ownD = cntD[tid];
    sd[tid] = ownD;
    __syncthreads();
    #pragma unroll
    for (int off = 1; off < 256; off <<= 1) {
        int t = (tid >= off) ? sd[tid - off] : 0;
        __syncthreads();
        sd[tid] += t;
        __syncthreads();
    }
    offD[tid] = sd[tid] - ownD;
    __syncthreads();

    // exclusive scan of cntS
    int ownS = cntS[tid];
    sd[tid] = ownS;
    __syncthreads();
    #pragma unroll
    for (int off = 1; off < 256; off <<= 1) {
        int t = (tid >= off) ? sd[tid - off] : 0;
        __syncthreads();
        sd[tid] += t;
        __syncthreads();
    }
    offS[tid] = sd[tid] - ownS;

    curD[tid] = offD[tid];
    curS[tid] = offS[tid];
    if (tid < NBUCK) {
        gBaseD[tid] = tid * BCAP + atomicAdd(&gCursD[tid], cntD[tid]);
        gBaseS[tid] = tid * BCAP + atomicAdd(&gCursS[tid], cntS[tid]);
    }
    __syncthreads();

    // LDS scatter into bucket-sorted order
    #pragma unroll
    for (int q = 0; q < 8; ++q) {
        int i = q * 256 + tid;
        if (i < nE) {
            int s = sE[i], d = dE[i];
            int slot  = atomicAdd(&curD[d >> 8], 1);
            sortD[slot] = ((uint)s << 16) | (uint)d;
            int slot2 = atomicAdd(&curS[s >> 8], 1);
            sortS[slot2] = (ushort)s;
        }
    }
    __syncthreads();

    // coalesced write-out (runs of same-bucket edges are contiguous)
    #pragma unroll
    for (int q = 0; q < 8; ++q) {
        int i = q * 256 + tid;
        if (i < nE) {
            uint v = sortD[i];
            int s = (int)(v >> 16), d = (int)(v & 0xFFFFu);
            int b = d >> 8;
            int gpos = gBaseD[b] + (i - offD[b]);
            if (gpos < (b + 1) * BCAP)
                pairsD[gpos] = ((uint)s << 8) | (uint)(d & 255);
            int sv = sortS[i];
            int bs = sv >> 8;
            int gpos2 = gBaseS[bs] + (i - offS[bs]);
            if (gpos2 < (bs + 1) * BCAP)
                srcB[gpos2] = (ushort)(sv & 255);
        }
    }
}

// ---------------- bucketB: role-split 392 blocks ----------------
// Blocks [0,196): per-bucket fine CSR (hist + scan + LDS-atomic slotting).
// Blocks [196,392): src 256-bin histogram -> scale_src. Both halves concurrent.
__global__ __launch_bounds__(256) void bucketB_kernel(
    const uint* __restrict__ pairsD, const ushort* __restrict__ srcB,
    const int* __restrict__ gCursD, const int* __restrict__ gCursS,
    ushort* __restrict__ edge_srcF, int2* __restrict__ begcnt,
    float* __restrict__ scale_src)
{
    __shared__ uint pE[BCAP];                     // 18.4 KB
    __shared__ int h[256], sd[256], curs[256];
    const int tid = threadIdx.x;

    if (blockIdx.x < NBUCK) {
        const int b = blockIdx.x;
        const int base = b * BCAP;
        const int cnt  = min(gCursD[b], BCAP);
        h[tid] = 0;
        __syncthreads();
        for (int i = tid; i < cnt; i += 256) {
            uint p = pairsD[base + i];
            pE[i] = p;
            atomicAdd(&h[p & 255], 1);
        }
        __syncthreads();
        int myc = h[tid];
        sd[tid] = myc;
        __syncthreads();
        #pragma unroll
        for (int off = 1; off < 256; off <<= 1) {
            int t = (tid >= off) ? sd[tid - off] : 0;
            __syncthreads();
            sd[tid] += t;
            __syncthreads();
        }
        int excl = sd[tid] - myc;
        int n = b * 256 + tid;
        if (n < N_NODES) begcnt[n] = make_int2(base + excl, myc);
        curs[tid] = excl;
        __syncthreads();
        for (int i = tid; i < cnt; i += 256) {
            uint p = pE[i];
            int slot = atomicAdd(&curs[p & 255], 1);
            edge_srcF[base + slot] = (ushort)(p >> 8);
        }
    } else {
        const int b = blockIdx.x - NBUCK;
        const int base = b * BCAP;
        const int cntS = min(gCursS[b], BCAP);
        h[tid] = 0;
        __syncthreads();
        for (int i = tid; i < cntS; i += 256)
            atomicAdd(&h[srcB[base + i]], 1);
        __syncthreads();
        int n = b * 256 + tid;
        if (n < N_NODES)
            scale_src[n] = rsqrtf(fmaxf((float)h[tid], 1.0f));
    }
}

// ---------------- W pre-split -> frag-major (all three weights) ----------------
__global__ __launch_bounds__(256) void wsplit_frag_kernel(
    const float* __restrict__ Wc, const float* __restrict__ W1,
    const float* __restrict__ W2, ushort* __restrict__ Wfc,
    ushort* __restrict__ Wf1, ushort* __restrict__ Wf2)
{
    int idx = blockIdx.x * 256 + threadIdx.x;
    const float* W; ushort* Wf; int K, off;
    if (idx < 4096)        { W = Wc; Wf = Wfc; K = 128; off = idx; }
    else if (idx < 12288)  { W = W1; Wf = Wf1; K = 256; off = idx - 4096; }
    else if (idx < 20480)  { W = W2; Wf = Wf2; K = 256; off = idx - 12288; }
    else return;
    int NK = K / 32;
    int l = off & 63;
    int kt = (K == 128) ? ((off >> 6) & 3) : ((off >> 6) & 7);
    int ct = (K == 128) ? (off >> 8) : (off >> 9);
    int col = ct * 16 + (l & 15);
    int kb  = kt * 32 + (l >> 4) * 8;
    frag8 vh, vl;
    #pragma unroll
    for (int q = 0; q < 8; ++q) {
        ushort hi, lo; split2(W[(size_t)(kb + q) * 256 + col], hi, lo);
        vh[q] = (short)hi; vl[q] = (short)lo;
    }
    ushort* dstp = Wf + ((size_t)(ct * NK + kt) * 2) * 512 + l * 8;
    *reinterpret_cast<frag8*>(dstp) = vh;
    *reinterpret_cast<frag8*>(dstp + 512) = vl;
}

// ---------------- fully fused: gather-aggregate + 3-layer MLP (R13 version) -----
template <int NK>
__device__ __forceinline__ void mfma_loop(
    const ushort* __restrict__ a0, const ushort* __restrict__ a1,
    const ushort* __restrict__ w0, const ushort* __restrict__ w1,
    const ushort* __restrict__ w2, const ushort* __restrict__ w3,
    f32x4 acc[2][4])
{
    #pragma unroll 2
    for (int kt = 0; kt < NK; ++kt) {
        const int o = kt * 1024;
        frag8 ah[2], al[2], bh[4], bl[4];
        ah[0] = *reinterpret_cast<const frag8*>(a0 + o);
        al[0] = *reinterpret_cast<const frag8*>(a0 + o + 512);
        ah[1] = *reinterpret_cast<const frag8*>(a1 + o);
        al[1] = *reinterpret_cast<const frag8*>(a1 + o + 512);
        bh[0] = *reinterpret_cast<const frag8*>(w0 + o);
        bl[0] = *reinterpret_cast<const frag8*>(w0 + o + 512);
        bh[1] = *reinterpret_cast<const frag8*>(w1 + o);
        bl[1] = *reinterpret_cast<const frag8*>(w1 + o + 512);
        bh[2] = *reinterpret_cast<const frag8*>(w2 + o);
        bl[2] = *reinterpret_cast<const frag8*>(w2 + o + 512);
        bh[3] = *reinterpret_cast<const frag8*>(w3 + o);
        bl[3] = *reinterpret_cast<const frag8*>(w3 + o + 512);
        #pragma unroll
        for (int m = 0; m < 2; ++m) {
            #pragma unroll
            for (int n = 0; n < 4; ++n) {
                acc[m][n] = __builtin_amdgcn_mfma_f32_16x16x32_bf16(ah[m], bh[n], acc[m][n], 0, 0, 0);
                acc[m][n] = __builtin_amdgcn_mfma_f32_16x16x32_bf16(ah[m], bl[n], acc[m][n], 0, 0, 0);
                acc[m][n] = __builtin_amdgcn_mfma_f32_16x16x32_bf16(al[m], bh[n], acc[m][n], 0, 0, 0);
            }
        }
    }
}

__global__ __launch_bounds__(256, 4) void fused_all_kernel(
    const float* __restrict__ feats, const ushort* __restrict__ edge_srcF,
    const int2* __restrict__ begcnt, const float* __restrict__ scale_src,
    const ushort* __restrict__ Wfc, const ushort* __restrict__ Wf1,
    const ushort* __restrict__ Wf2, const float* __restrict__ bc,
    const float* __restrict__ b1, const float* __restrict__ b2,
    float* __restrict__ out, int M)
{
    // bytes [0,16384): fb_l1 (layer-1 A operand) then full fb (layer-2/3, 32KB)
    // bytes [16384,33280): hb = f32 agg bounce [32][132] (dead after phase B)
    __shared__ ushort fb[16640];   // 33280 B
    float* hb = (float*)&fb[8192];

    const int tid  = threadIdx.x;
    const int lane = tid & 63;
    const int wv   = tid >> 6;
    const int blk  = blockIdx.x;
    const int row0 = blk * 32;
    const int fr   = lane & 15;
    const int lg   = lane >> 4;
    const int fh   = fr >> 3;

    // ---- phase A: gather-aggregate (16 threads/node, 2 passes) ----
    {
        const int g   = tid >> 4;     // 0..15
        const int l16 = tid & 15;
        #pragma unroll
        for (int p = 0; p < 2; ++p) {
            int nl = p * 16 + g;
            int n  = row0 + nl;
            float4 a0 = make_float4(0, 0, 0, 0), a1 = make_float4(0, 0, 0, 0);
            float4 c0 = make_float4(0, 0, 0, 0), c1 = make_float4(0, 0, 0, 0);
            if (n < M) {
                int2 bcn = begcnt[n];
                int j = bcn.x, jend = bcn.x + bcn.y;
                for (; j + 1 < jend; j += 2) {
                    int s0 = edge_srcF[j], s1 = edge_srcF[j + 1];
                    float sc0 = scale_src[s0], sc1 = scale_src[s1];
                    const float* f0 = feats + (size_t)s0 * IN_DIM + l16 * 4;
                    const float* f1 = feats + (size_t)s1 * IN_DIM + l16 * 4;
                    float4 v0 = *reinterpret_cast<const float4*>(f0);
                    float4 w0 = *reinterpret_cast<const float4*>(f0 + 64);
                    float4 v1 = *reinterpret_cast<const float4*>(f1);
                    float4 w1 = *reinterpret_cast<const float4*>(f1 + 64);
                    a0.x = fmaf(v0.x, sc0, a0.x); a0.y = fmaf(v0.y, sc0, a0.y);
                    a0.z = fmaf(v0.z, sc0, a0.z); a0.w = fmaf(v0.w, sc0, a0.w);
                    a1.x = fmaf(w0.x, sc0, a1.x); a1.y = fmaf(w0.y, sc0, a1.y);
                    a1.z = fmaf(w0.z, sc0, a1.z); a1.w = fmaf(w0.w, sc0, a1.w);
                    c0.x = fmaf(v1.x, sc1, c0.x); c0.y = fmaf(v1.y, sc1, c0.y);
                    c0.z = fmaf(v1.z, sc1, c0.z); c0.w = fmaf(v1.w, sc1, c0.w);
                    c1.x = fmaf(w1.x, sc1, c1.x); c1.y = fmaf(w1.y, sc1, c1.y);
                    c1.z = fmaf(w1.z, sc1, c1.z); c1.w = fmaf(w1.w, sc1, c1.w);
                }
                if (j < jend) {
                    int s0 = edge_srcF[j];
                    float sc0 = scale_src[s0];
                    const float* f0 = feats + (size_t)s0 * IN_DIM + l16 * 4;
                    float4 v0 = *reinterpret_cast<const float4*>(f0);
                    float4 w0 = *reinterpret_cast<const float4*>(f0 + 64);
                    a0.x = fmaf(v0.x, sc0, a0.x); a0.y = fmaf(v0.y, sc0, a0.y);
                    a0.z = fmaf(v0.z, sc0, a0.z); a0.w = fmaf(v0.w, sc0, a0.w);
                    a1.x = fmaf(w0.x, sc0, a1.x); a1.y = fmaf(w0.y, sc0, a1.y);
                    a1.z = fmaf(w0.z, sc0, a1.z); a1.w = fmaf(w0.w, sc0, a1.w);
                }
                float di = rsqrtf(fmaxf((float)bcn.y, 1.0f));
                a0.x = (a0.x + c0.x) * di; a0.y = (a0.y + c0.y) * di;
                a0.z = (a0.z + c0.z) * di; a0.w = (a0.w + c0.w) * di;
                a1.x = (a1.x + c1.x) * di; a1.y = (a1.y + c1.y) * di;
                a1.z = (a1.z + c1.z) * di; a1.w = (a1.w + c1.w) * di;
            }
            *reinterpret_cast<float4*>(&hb[nl * 132 + l16 * 4])      = a0;
            *reinterpret_cast<float4*>(&hb[nl * 132 + 64 + l16 * 4]) = a1;
        }
    }
    __syncthreads();

    // ---- phase B: hb -> fb_l1 (frag-major, 2 tiles x 4 kt x 2 planes) ----
    #pragma unroll
    for (int it = 0; it < 2; ++it) {
        int idx = it * 256 + tid;              // 0..511
        int l = idx & 63, kt = (idx >> 6) & 3, tile = idx >> 8;
        const float* srcp = &hb[(tile * 16 + (l & 15)) * 132 + kt * 32 + (l >> 4) * 8];
        frag8 vh, vl;
        #pragma unroll
        for (int q = 0; q < 8; ++q) {
            ushort hi, lo; split2(srcp[q], hi, lo);
            vh[q] = (short)hi; vl[q] = (short)lo;
        }
        ushort* dstp = fb + ((tile * 4 + kt) * 2) * 512 + l * 8;
        *reinterpret_cast<frag8*>(dstp) = vh;
        *reinterpret_cast<frag8*>(dstp + 512) = vl;
    }
    __syncthreads();

    // swizzled per-thread write base for layer-1/2 epilogues
    ushort* fbase = fb + wv * 2048 + (lg << 5) + (fr & 7);
    const int lsw = (lane * 8) ^ ((lane >> 4) << 3);

    f32x4 acc[2][4];

    // ---- layer 1: K=128 (NK=4), A from fb_l1 ----
    {
        const ushort* a0 = fb + lane * 8;
        const ushort* a1 = fb + 4096 + lane * 8;
        const ushort* w0 = Wfc + ((size_t)(wv * 4 + 0) * 4 * 2) * 512 + lane * 8;
        const ushort* w1 = Wfc + ((size_t)(wv * 4 + 1) * 4 * 2) * 512 + lane * 8;
        const ushort* w2 = Wfc + ((size_t)(wv * 4 + 2) * 4 * 2) * 512 + lane * 8;
        const ushort* w3 = Wfc + ((size_t)(wv * 4 + 3) * 4 * 2) * 512 + lane * 8;
        #pragma unroll
        for (int m = 0; m < 2; ++m)
            #pragma unroll
            for (int n = 0; n < 4; ++n) acc[m][n] = (f32x4)(0.f);
        mfma_loop<4>(a0, a1, w0, w1, w2, w3, acc);
    }
    __syncthreads();   // all fb_l1 reads done before epilogue overwrites

    // layer-1 epilogue: silu -> split -> fb (swizzled direct)
    #pragma unroll
    for (int n = 0; n < 4; ++n) {
        float b = bc[wv * 64 + n * 16 + fr];
        const int kseg = 2 * (n & 1) + fh;
        const int noff = (n >> 1) * 1024 + kseg * 128;
        #pragma unroll
        for (int m = 0; m < 2; ++m) {
            f32x4 v = acc[m][n];
            #pragma unroll
            for (int q = 0; q < 4; ++q) {
                float s = silu_fast(v[q] + b);
                ushort hi, lo; split2(s, hi, lo);
                const int o = m * 8192 + noff + (q ^ kseg) * 8;
                fbase[o]       = hi;
                fbase[o + 512] = lo;
            }
        }
    }
    __syncthreads();

    // ---- layer 2: K=256 (NK=8), A from fb (swizzled) ----
    {
        const ushort* a0 = fb + lsw;
        const ushort* a1 = fb + 8192 + lsw;
        const ushort* w0 = Wf1 + ((size_t)(wv * 4 + 0) * 8 * 2) * 512 + lane * 8;
        const ushort* w1 = Wf1 + ((size_t)(wv * 4 + 1) * 8 * 2) * 512 + lane * 8;
        const ushort* w2 = Wf1 + ((size_t)(wv * 4 + 2) * 8 * 2) * 512 + lane * 8;
        const ushort* w3 = Wf1 + ((size_t)(wv * 4 + 3) * 8 * 2) * 512 + lane * 8;
        #pragma unroll
        for (int m = 0; m < 2; ++m)
            #pragma unroll
            for (int n = 0; n < 4; ++n) acc[m][n] = (f32x4)(0.f);
        mfma_loop<8>(a0, a1, w0, w1, w2, w3, acc);
    }
    __syncthreads();   // all fb reads done before overwrite

    // layer-2 epilogue -> fb (swizzled direct)
    #pragma unroll
    for (int n = 0; n < 4; ++n) {
        float b = b1[wv * 64 + n * 16 + fr];
        const int kseg = 2 * (n & 1) + fh;
        const int noff = (n >> 1) * 1024 + kseg * 128;
        #pragma unroll
        for (int m = 0; m < 2; ++m) {
            f32x4 v = acc[m][n];
            #pragma unroll
            for (int q = 0; q < 4; ++q) {
                float s = silu_fast(v[q] + b);
                ushort hi, lo; split2(s, hi, lo);
                const int o = m * 8192 + noff + (q ^ kseg) * 8;
                fbase[o]       = hi;
                fbase[o + 512] = lo;
            }
        }
    }
    __syncthreads();

    // ---- layer 3: K=256 (NK=8), A from fb (swizzled) ----
    {
        const ushort* a0 = fb + lsw;
        const ushort* a1 = fb + 8192 + lsw;
        const ushort* w0 = Wf2 + ((size_t)(wv * 4 + 0) * 8 * 2) * 512 + lane * 8;
        const ushort* w1 = Wf2 + ((size_t)(wv * 4 + 1) * 8 * 2) * 512 + lane * 8;
        const ushort* w2 = Wf2 + ((size_t)(wv * 4 + 2) * 8 * 2) * 512 + lane * 8;
        const ushort* w3 = Wf2 + ((size_t)(wv * 4 + 3) * 8 * 2) * 512 + lane * 8;
        #pragma unroll
        for (int m = 0; m < 2; ++m)
            #pragma unroll
            for (int n = 0; n < 4; ++n) acc[m][n] = (f32x4)(0.f);
        mfma_loop<8>(a0, a1, w0, w1, w2, w3, acc);
    }

    // layer-3 epilogue: direct f32 global stores (64B-contiguous per 16 lanes)
    #pragma unroll
    for (int n = 0; n < 4; ++n) {
        int col = wv * 64 + n * 16 + fr;
        float b = b2[col];
        #pragma unroll
        for (int m = 0; m < 2; ++m) {
            int rowb = row0 + m * 16 + lg * 4;
            f32x4 v = acc[m][n];
            #pragma unroll
            for (int q = 0; q < 4; ++q) {
                int row = rowb + q;
                if (row < M)
                    out[(size_t)row * OUT_DIM + col] = silu_fast(v[q] + b);
            }
        }
    }
}

extern "C" void kernel_launch(void* const* d_in, const int* in_sizes, int n_in,
                              void* d_out, int out_size, void* d_ws, size_t ws_size,
                              hipStream_t stream)
{
    const float* feats  = (const float*)d_in[0];
    const float* W_conv = (const float*)d_in[1];
    const float* b_conv = (const float*)d_in[2];
    const float* W1     = (const float*)d_in[3];
    const float* b1     = (const float*)d_in[4];
    const float* W2     = (const float*)d_in[5];
    const float* b2     = (const float*)d_in[6];
    const int*   src    = (const int*)d_in[7];
    const int*   dst    = (const int*)d_in[8];

    // workspace layout (bytes):
    //   [0, 784)                 gCursD (196 ints)
    //   [1024, 1808)             gCursS
    //   [4096, 404,096)          begcnt (50000 int2)
    //   [404,096, 604,096)       scale_src (N f32)
    //   [1,000,000, 4,612,672)   pairsD  (196 x 4608 uint)
    //   [4,612,672, 6,419,008)   srcB    (196 x 4608 ushort)
    //   [6,420,480, 8,226,816)   edge_srcF (196 x 4608 ushort, padded CSR)
    //   [80,600,064, 81,255,424) Wfc / Wf1 / Wf2 (frag-major bf16 planes)
    char* ws = (char*)d_ws;
    int*    gCursD    = (int*)(ws + 0);
    int*    gCursS    = (int*)(ws + 1024);
    int2*   begcnt    = (int2*)(ws + 4096);
    float*  scale_src = (float*)(ws + 404096);
    uint*   pairsD    = (uint*)(ws + 1000000);
    ushort* srcB      = (ushort*)(ws + 4612672);
    ushort* edge_srcF = (ushort*)(ws + 6420480);
    ushort* Wfc       = (ushort*)(ws + 80600064);
    ushort* Wf1       = (ushort*)(ws + 80731136);
    ushort* Wf2       = (ushort*)(ws + 80993280);

    hipMemsetAsync(ws, 0, 2048, stream);   // zero gCursD + gCursS

    const int ablocks = (N_EDGES + 2047) / 2048;   // 391
    bucketA_kernel<<<ablocks, 256, 0, stream>>>(src, dst, gCursD, gCursS, pairsD, srcB, N_EDGES);
    bucketB_kernel<<<NBUCK * 2, 256, 0, stream>>>(pairsD, srcB, gCursD, gCursS,
                                                  edge_srcF, begcnt, scale_src);

    wsplit_frag_kernel<<<80, 256, 0, stream>>>(W_conv, W1, W2, Wfc, Wf1, Wf2);

    const int gblocks = (N_NODES + 31) / 32;   // 1563
    fused_all_kernel<<<gblocks, 256, 0, stream>>>(feats, edge_srcF, begcnt, scale_src,
                                                  Wfc, Wf1, Wf2, b_conv, b1, b2,
                                                  (float*)d_out, N_NODES);
}